// Round 14
// baseline (172.671 us; speedup 1.0000x reference)
//
#include <hip/hip_runtime.h>

#define BT     16
#define NN     10242
#define CC     64
#define KK     9
#define NBR_   7
#define OO     64
#define MT     16            // rows (nodes) per group-tile
#define RS     584           // LDS itp row stride in bf16 (16B-aligned)
#define KT     18            // K tiles of 32
#define SLOTS  1282          // per-XCD tasks: 2 bt x 641 nt
#define NB     512           // blocks: 64 per XCD, 2 sequential per CU
#define NIV    6             // intervals: ceil(1282 / 256)

using frag  = __attribute__((ext_vector_type(8))) short;   // 8 bf16 (4 VGPRs)
using f32x4 = __attribute__((ext_vector_type(4))) float;
using f32x2 = __attribute__((ext_vector_type(2))) float;

static __device__ __forceinline__ unsigned short f2bf(float f) {
    union { float f; unsigned u; } v; v.f = f;
    unsigned r = v.u + 0x7fffu + ((v.u >> 16) & 1u);   // RNE
    return (unsigned short)(r >> 16);
}

// packed pair via v_cvt_pk_bf16_f32 (native RNE pack — bit-identical to f2bf)
static __device__ __forceinline__ unsigned pk2(float a, float b) {
    unsigned r;
    asm("v_cvt_pk_bf16_f32 %0, %1, %2" : "=v"(r) : "v"(a), "v"(b));
    return r;
}

// q-permutation shared by producer and weight pack:
//   k in [0,8): q = (k>>2)*256 + c*4 + (k&3);  k==8: q = 512 + c
// wb[((t*4+ct)*64+lane)*8+j] = bf16(w[o][c][k]), q=t*32+(lane>>4)*8+j, o=ct*16+(lane&15)
__global__ void pack_w_kernel(const float* __restrict__ w, unsigned short* __restrict__ wb) {
    int i = blockIdx.x * blockDim.x + threadIdx.x;
    if (i >= KT * 4 * 64 * 8) return;
    int j  = i & 7;
    int l  = (i >> 3) & 63;
    int ct = (i >> 9) & 3;
    int t  = i >> 11;
    int q  = t * 32 + (l >> 4) * 8 + j;
    int o  = ct * 16 + (l & 15);
    int c, k;
    if (q < 512) { c = (q & 255) >> 2; k = (q >> 8) * 4 + (q & 3); }
    else         { c = q - 512;        k = 8; }
    wb[i] = f2bf(w[(o * CC + c) * KK + k]);
}

__global__ __launch_bounds__(1024, 4) void sphere_conv_kernel(
    const float* __restrict__ x,      // (BT, N, C)
    const int*   __restrict__ index,  // (N, NBR)
    const float* __restrict__ m,      // (N, NBR, K)
    const unsigned short* __restrict__ wb,  // packed B frags (bf16 bits)
    const float* __restrict__ bias,   // (O,)
    float*       __restrict__ out)    // (BT, N, O)
{
    // B staged ONCE per block: L2 B-traffic 738MB -> 512 x 72KB = 38MB.
    __shared__ unsigned short B_s[KT * 4 * 64 * 8];   // 73728 B
    __shared__ unsigned short itp_s[4][MT * RS];      // 4 x 18688 B
    // total 148480 B -> 1 block/CU, 16 waves (gfx950 allows >64KB static LDS)

    const int tid  = threadIdx.x;
    const int w    = tid >> 6;          // 0..15
    const int lane = tid & 63;
    const int g    = w >> 2;            // group 0..3 (one 16-node tile each)
    const int wg   = w & 3;             // wave within group

    const int bid = blockIdx.x;
    const int xcd = bid & 7;            // XCD-ownership: bt in {2c, 2c+1}
    const int q   = bid >> 3;           // 0..63 within the XCD

    // ---- stage packed B (72 chunks x 1024B) into LDS via global_load_lds ----
    {
        const char* wbc = (const char*)wb;
        #pragma unroll
        for (int t = 0; t < 5; ++t) {
            const int c = t * 16 + w;   // each (t,w) stages one 1KB chunk
            if (c < 72) {
                const void* src = wbc + c * 1024 + lane * 16;
                __builtin_amdgcn_global_load_lds(
                    (const __attribute__((address_space(1))) void*)src,
                    (__attribute__((address_space(3))) void*)((char*)B_s + c * 1024),
                    16, 0, 0);
            }
        }
    }
    __syncthreads();    // barrier drain completes the B staging

    for (int i = 0; i < NIV; ++i) {
        // bijective task map: ss = i*256 + q*4 + g covers [0,1536) once;
        // guard < 1282. Group's slot: btl selects bt half, nt sweeps in order
        // -> per-XCD gather working set = one 2.62MB x-slice (R11 locality).
        const int  ss    = i * 256 + q * 4 + g;
        const bool valid = (ss < SLOTS);
        const int  ssc   = valid ? ss : 0;
        const int  btl   = (ssc >= 641) ? 1 : 0;
        const int  nt    = ssc - btl * 641;
        const int  bt    = xcd * 2 + btl;
        const int  n0    = nt * MT;

        if (valid) {
            // ---------- Producer: wave wg = rows wg*4..wg*4+3, lane = channel
            const float* xbt = x + (size_t)bt * NN * CC;

            int nu[4];
            #pragma unroll
            for (int r = 0; r < 4; ++r) {
                const int n = n0 + wg * 4 + r;
                // clamp (reads in-bounds; junk rows never stored) + wave-uniform
                // so index/m go through scalar loads (K$/L2)
                nu[r] = __builtin_amdgcn_readfirstlane(n < NN ? n : (NN - 1));
            }

            float xv[4][NBR_];
            #pragma unroll
            for (int r = 0; r < 4; ++r) {
                const int* ip = index + nu[r] * NBR_;          // SGPR -> s_load
                #pragma unroll
                for (int j = 0; j < NBR_; ++j)
                    xv[r][j] = xbt[(size_t)ip[j] * CC + lane]; // 256B gather
            }

            #pragma unroll
            for (int r = 0; r < 4; ++r) {
                const int ns = wg * 4 + r;
                const float* mp = m + nu[r] * (NBR_ * KK);     // SGPR -> s_load

                // Packed-FP32 interp (R12): v_pk_fma_f32, same per-k order ->
                // bit-identical results.
                f32x2 acc2[4];
                float acc8 = 0.f;
                #pragma unroll
                for (int p = 0; p < 4; ++p) acc2[p] = (f32x2){0.f, 0.f};
                #pragma unroll
                for (int j = 0; j < NBR_; ++j) {
                    const float xvj = xv[r][j];
                    const f32x2 xv2 = (f32x2){xvj, xvj};
                    #pragma unroll
                    for (int p = 0; p < 4; ++p) {
                        const f32x2 m2 = (f32x2){mp[j * KK + 2 * p],
                                                 mp[j * KK + 2 * p + 1]};
                        acc2[p] = __builtin_elementwise_fma(xv2, m2, acc2[p]);
                    }
                    acc8 = fmaf(xvj, mp[j * KK + 8], acc8);
                }

                uint2 q0, q1;
                q0.x = pk2(acc2[0][0], acc2[0][1]);
                q0.y = pk2(acc2[1][0], acc2[1][1]);
                q1.x = pk2(acc2[2][0], acc2[2][1]);
                q1.y = pk2(acc2[3][0], acc2[3][1]);
                unsigned short* row = &itp_s[g][ns * RS];
                *(uint2*)(&row[lane * 4])       = q0;          // 8B, 2-way free
                *(uint2*)(&row[256 + lane * 4]) = q1;
                row[512 + lane] = f2bf(acc8);
            }
        }
        __syncthreads();    // group tiles visible to consumers

        if (valid) {
            // ---------- Consumer: wave = 16 rows x 16 cols, B from LDS ------
            const int ct   = wg;
            const int am   = lane & 15;
            const int half = lane >> 4;

            f32x4 cacc = (f32x4){0.f, 0.f, 0.f, 0.f};
            const unsigned short* arow = &itp_s[g][am * RS + half * 8];

            #pragma unroll
            for (int t = 0; t < KT; ++t) {
                const frag a = *(const frag*)(arow + t * 32);               // ds_read_b128
                const frag b = *(const frag*)&B_s[((t * 4 + ct) * 64 + lane) * 8]; // ds_read_b128
                cacc = __builtin_amdgcn_mfma_f32_16x16x32_bf16(a, b, cacc, 0, 0, 0);
            }

            // Epilogue: bias + non-temporal store (out never re-read; keep the
            // write stream from evicting the x-slice out of L2 — R11)
            const size_t obase = (size_t)bt * NN * OO;
            const int o  = ct * 16 + am;
            const float bo = bias[o];
            #pragma unroll
            for (int ii = 0; ii < 4; ++ii) {
                const int n = n0 + half * 4 + ii;
                if (n < NN)
                    __builtin_nontemporal_store(cacc[ii] + bo,
                                                &out[obase + (size_t)n * OO + o]);
            }
        }
        __syncthreads();    // itp_s free for next interval's producer
    }
}

extern "C" void kernel_launch(void* const* d_in, const int* in_sizes, int n_in,
                              void* d_out, int out_size, void* d_ws, size_t ws_size,
                              hipStream_t stream) {
    const float* x      = (const float*)d_in[0];
    const int*   index  = (const int*)  d_in[1];
    const float* m      = (const float*)d_in[2];
    const float* conv_w = (const float*)d_in[3];
    const float* conv_b = (const float*)d_in[4];
    float* out = (float*)d_out;
    unsigned short* wb = (unsigned short*)d_ws;   // 73728 B

    {   // pack weights into MFMA B-fragment order
        const int total = KT * 4 * 64 * 8;
        pack_w_kernel<<<(total + 255) / 256, 256, 0, stream>>>(conv_w, wb);
    }
    {   // B-in-LDS persistent-ish blocks: 64 per XCD, 4 tiles per interval
        dim3 grid(NB);                            // 512 x 1024 threads
        sphere_conv_kernel<<<grid, 1024, 0, stream>>>(x, index, m, wb, conv_b, out);
    }
}